// Round 3
// baseline (1840.250 us; speedup 1.0000x reference)
//
#include <hip/hip_runtime.h>
#include <cmath>

// ---------------- constants ----------------
constexpr int BB    = 8;     // batch
constexpr int LS    = 57;    // spectra tokens
constexpr int LG    = 9;     // gaia tokens
constexpr int RS    = BB*LS; // 456
constexpr int RG    = BB*LG; // 72
constexpr int DM    = 512;   // d_model
constexpr int DPROJ = 2320;
constexpr int DIN   = 1024;
constexpr int NH    = 16;    // mamba heads
constexpr int HD    = 64;    // mamba headdim
constexpr int NLAY  = 10;

constexpr int SP_IN  = 4;    // split-K for in-proj  (K=512  -> 128/split)
constexpr int SP_OUT = 8;    // split-K for out-proj (K=1024 -> 128/split)
constexpr int SP_ATT = 4;    // split-K for attention gemms (K=512 -> 128/split)

__device__ __forceinline__ float siluf(float x){ return x / (1.f + expf(-x)); }

// ---------------- tokenize ----------------
__global__ __launch_bounds__(512) void tokenize_k(
    const float* __restrict__ x, const float* __restrict__ w, const float* __restrict__ bias,
    float* __restrict__ out, int in_dim, int tok_dim, int ntok)
{
    int t = blockIdx.x, b = blockIdx.y, d = threadIdx.x;
    __shared__ float xv[64];
    if (d < tok_dim) {
        int idx = t*tok_dim + d;
        xv[d] = (idx < in_dim) ? x[(size_t)b*in_dim + idx] : 0.f;
    }
    __syncthreads();
    float acc = bias[d];
    for (int k=0;k<tok_dim;k++) acc += xv[k]*w[(size_t)k*DM + d];
    out[(size_t)(b*ntok + t)*DM + d] = acc;
}

// ---------------- split-K f32 GEMM -> partials ----------------
// partial[split][M][N] = A[M][k-slice] @ B (TB=false: B=[K][N]; TB=true: B=[N][K])
// BM=64, 256 threads, per-thread 4 x TN outputs, double-buffered LDS, 1 barrier/iter.
struct GemmJob {
    const float* A; const float* B; float* part; int M;
};

template<int BN, int TN, bool TB, int NSPLIT>
__global__ __launch_bounds__(256) void gemm_ps(GemmJob j0, GemmJob j1, GemmJob j2, int N, int K)
{
    const int z = blockIdx.z;
    const int job = z / NSPLIT, split = z % NSPLIT;
    GemmJob jb = (job==0) ? j0 : (job==1 ? j1 : j2);
    const int bm = blockIdx.y*64, bn = blockIdx.x*BN;
    const int M = jb.M;
    if (bm >= M) return;
    __shared__ float As[2][16][68];
    __shared__ float Bs[2][16][BN+4];
    const int tid = threadIdx.x, tx = tid & 15, ty = tid >> 4;
    const float* __restrict__ A  = jb.A;
    const float* __restrict__ Bm = jb.B;
    float acc[4][TN] = {};

    const int arow = tid>>2, akb = (tid&3)*4;
    float4 ra, rb0, rb1;

    auto zero4 = [](){ float4 zz; zz.x=0.f; zz.y=0.f; zz.z=0.f; zz.w=0.f; return zz; };

    auto loadT = [&](int k0){
        ra = (bm+arow < M) ? *(const float4*)(A + (size_t)(bm+arow)*K + k0 + akb) : zero4();
        if constexpr (!TB) {
            const int kr = tid>>4, c4 = (tid&15)*4;
            rb0 = (bn+c4 < N) ? *(const float4*)(Bm + (size_t)(k0+kr)*N + bn + c4) : zero4();
            if constexpr (TN==8)
                rb1 = (bn+64+c4 < N) ? *(const float4*)(Bm + (size_t)(k0+kr)*N + bn + 64 + c4) : zero4();
        } else {
            const int nr = tid>>2, kb = (tid&3)*4;
            rb0 = (bn+nr < N) ? *(const float4*)(Bm + (size_t)(bn+nr)*K + k0 + kb) : zero4();
        }
    };
    auto storeT = [&](int buf){
        As[buf][akb+0][arow] = ra.x;
        As[buf][akb+1][arow] = ra.y;
        As[buf][akb+2][arow] = ra.z;
        As[buf][akb+3][arow] = ra.w;
        if constexpr (!TB) {
            const int kr = tid>>4, c4 = (tid&15)*4;
            *(float4*)&Bs[buf][kr][c4] = rb0;
            if constexpr (TN==8) *(float4*)&Bs[buf][kr][64+c4] = rb1;
        } else {
            const int nr = tid>>2, kb = (tid&3)*4;
            Bs[buf][kb+0][nr] = rb0.x;
            Bs[buf][kb+1][nr] = rb0.y;
            Bs[buf][kb+2][nr] = rb0.z;
            Bs[buf][kb+3][nr] = rb0.w;
        }
    };

    const int Kper = K/NSPLIT;
    const int koff = split*Kper;
    const int nk = Kper/16;
    loadT(koff);
    storeT(0);
    __syncthreads();
    for (int t=0; t<nk; ++t){
        const int cur = t & 1;
        if (t+1 < nk) loadT(koff + (t+1)*16);
        #pragma unroll
        for (int kk=0; kk<16; ++kk){
            float4 av = *(const float4*)&As[cur][kk][ty*4];
            float a[4] = {av.x, av.y, av.z, av.w};
            float b[TN];
            #pragma unroll
            for (int g=0; g<TN/4; ++g){
                float4 bv = *(const float4*)&Bs[cur][kk][tx*TN + g*4];
                b[g*4+0]=bv.x; b[g*4+1]=bv.y; b[g*4+2]=bv.z; b[g*4+3]=bv.w;
            }
            #pragma unroll
            for (int i=0;i<4;i++)
                #pragma unroll
                for (int j=0;j<TN;j++) acc[i][j] = fmaf(a[i], b[j], acc[i][j]);
        }
        if (t+1 < nk) storeT(cur^1);
        __syncthreads();
    }

    float* __restrict__ P = jb.part + (size_t)split*M*N;
    #pragma unroll
    for (int i=0;i<4;i++){
        int m = bm + ty*4 + i;
        if (m < M){
            #pragma unroll
            for (int j=0;j<TN;j++){
                int n = bn + tx*TN + j;
                if (n < N) P[(size_t)m*N + n] = acc[i][j];
            }
        }
    }
}

// ---------------- reduce partials (+bias, +res) ----------------
struct RJob { const float* part; const float* bias; const float* res; float* C; int M; };

template<int NS>
__global__ __launch_bounds__(256) void reduce_k(RJob j0, RJob j1, int N)
{
    RJob j = blockIdx.y ? j1 : j0;
    const size_t total = (size_t)j.M*N;
    const size_t i4 = ((size_t)blockIdx.x*256 + threadIdx.x)*4;
    if (i4 >= total) return;
    float4 s = *(const float4*)(j.part + i4);
    #pragma unroll
    for (int t=1;t<NS;t++){
        const float4 v = *(const float4*)(j.part + (size_t)t*total + i4);
        s.x+=v.x; s.y+=v.y; s.z+=v.z; s.w+=v.w;
    }
    const int n = (int)(i4 % (size_t)N);
    if (j.bias){ s.x+=j.bias[n]; s.y+=j.bias[n+1]; s.z+=j.bias[n+2]; s.w+=j.bias[n+3]; }
    if (j.res){ const float4 r = *(const float4*)(j.res + i4); s.x+=r.x; s.y+=r.y; s.z+=r.z; s.w+=r.w; }
    *(float4*)(j.C + i4) = s;
}

// ---------------- fused conv1d+silu+softplus+SSM scan, per (head,batch,stack) ----------------
// reads zx as sum of SP_IN partials; 1 barrier/step; next-row software prefetch.
__global__ __launch_bounds__(256) void mamba_scan(
    const float* __restrict__ pS, const float* __restrict__ pG,
    const float* __restrict__ cw_s, const float* __restrict__ cw_g,
    const float* __restrict__ cb_s, const float* __restrict__ cb_g,
    const float* __restrict__ dtb_s, const float* __restrict__ dtb_g,
    const float* __restrict__ al_s, const float* __restrict__ al_g,
    const float* __restrict__ Dw_s, const float* __restrict__ Dw_g,
    float* __restrict__ y_s, float* __restrict__ y_g)
{
    const int h = blockIdx.x, b = blockIdx.y, st = blockIdx.z;
    const float* pin = st ? pG : pS;
    const size_t pstr = (size_t)(st ? RG : RS) * DPROJ;
    const float* cw  = st ? cw_g  : cw_s;
    const float* cb  = st ? cb_g  : cb_s;
    const float* dtb = st ? dtb_g : dtb_s;
    const float* al  = st ? al_g  : al_s;
    const float* Dw  = st ? Dw_g  : Dw_s;
    float* y = st ? y_g : y_s;
    const int L = st ? LG : LS;

    const int t = threadIdx.x;
    __shared__ float conv[2][320];  // [0..63]=xh(head h), [64..191]=B, [192..319]=C

    auto loadsum = [&](size_t off){
        return pin[off] + pin[pstr + off] + pin[2*pstr + off] + pin[3*pstr + off];
    };

    const int cA  = t;
    const int chA = (cA < 64) ? (h*HD + cA) : (960 + cA);
    float wA[4]; float cbA;
    #pragma unroll
    for (int k=0;k<4;k++) wA[k] = cw[chA*4 + k];
    cbA = cb[chA];
    const bool hasB = (t < 64);
    int chB = 1216 + t;
    float wB[4] = {0,0,0,0}; float cbB = 0.f;
    if (hasB) {
        #pragma unroll
        for (int k=0;k<4;k++) wB[k] = cw[chB*4 + k];
        cbB = cb[chB];
    }

    const float Ah     = -expf(al[h]);
    const float dtbias = dtb[h];
    const float Dh     = Dw[h];

    const int p = t >> 2, ng = t & 3;
    float hst[32];
    #pragma unroll
    for (int j=0;j<32;j++) hst[j] = 0.f;

    float histA0=0.f, histA1=0.f, histA2=0.f;
    float histB0=0.f, histB1=0.f, histB2=0.f;

    float rawA, rawB = 0.f, dtraw;
    {
        const size_t rowbase = (size_t)(b*L + 0)*DPROJ;
        rawA = loadsum(rowbase + 1024 + chA);
        if (hasB) rawB = loadsum(rowbase + 1024 + chB);
        dtraw = loadsum(rowbase + 2304 + h);
    }

    for (int l=0; l<L; ++l) {
        float nA = 0.f, nB = 0.f, nD = 0.f;
        if (l+1 < L) {
            const size_t rowbase = (size_t)(b*L + l+1)*DPROJ;
            nA = loadsum(rowbase + 1024 + chA);
            if (hasB) nB = loadsum(rowbase + 1024 + chB);
            nD = loadsum(rowbase + 2304 + h);
        }
        const int cbuf = l & 1;

        float accA = cbA + wA[0]*histA0 + wA[1]*histA1 + wA[2]*histA2 + wA[3]*rawA;
        conv[cbuf][cA] = siluf(accA);
        histA0 = histA1; histA1 = histA2; histA2 = rawA;
        if (hasB) {
            float accB = cbB + wB[0]*histB0 + wB[1]*histB1 + wB[2]*histB2 + wB[3]*rawB;
            conv[cbuf][256 + t] = siluf(accB);
            histB0 = histB1; histB1 = histB2; histB2 = rawB;
        }
        __syncthreads();

        float dtv = dtraw + dtbias;
        dtv = (dtv > 20.f) ? dtv : log1pf(expf(dtv));
        const float dA   = expf(dtv * Ah);
        const float xh   = conv[cbuf][p];
        const float coef = dtv * xh;
        const float* Bv  = &conv[cbuf][64  + ng*32];
        const float* Cv  = &conv[cbuf][192 + ng*32];
        float ysum = 0.f;
        #pragma unroll
        for (int j=0;j<32;j++){
            hst[j] = dA*hst[j] + coef*Bv[j];
            ysum  += hst[j]*Cv[j];
        }
        ysum += __shfl_xor(ysum, 1, 64);
        ysum += __shfl_xor(ysum, 2, 64);
        if (ng == 0)
            y[(size_t)(b*L + l)*DIN + h*HD + p] = ysum + Dh*xh;

        rawA = nA; rawB = nB; dtraw = nD;
    }
}

// ---------------- gated RMSNorm (z read from in-proj partials) ----------------
__global__ __launch_bounds__(256) void gated_rmsnorm(
    const float* __restrict__ y_s, const float* __restrict__ pS, const float* __restrict__ nw_s, float* __restrict__ o_s,
    const float* __restrict__ y_g, const float* __restrict__ pG, const float* __restrict__ nw_g, float* __restrict__ o_g)
{
    int r = blockIdx.x, t = threadIdx.x;
    int st = (r >= RS);
    int row = st ? r - RS : r;
    const float* y   = (st ? y_g : y_s) + (size_t)row*DIN;
    const float* pin = st ? pG : pS;
    const size_t pstr = (size_t)(st ? RG : RS) * DPROJ;
    const size_t zoff = (size_t)row*DPROJ;
    const float* nw = st ? nw_g : nw_s;
    float* o = (st ? o_g : o_s) + (size_t)row*DIN;

    float g[4]; float s2 = 0.f;
    #pragma unroll
    for (int i=0;i<4;i++){
        int idx = t + i*256;
        float zv = pin[zoff+idx] + pin[pstr+zoff+idx] + pin[2*pstr+zoff+idx] + pin[3*pstr+zoff+idx];
        float gv = y[idx] * siluf(zv);
        g[i] = gv; s2 += gv*gv;
    }
    #pragma unroll
    for (int o2=32;o2;o2>>=1) s2 += __shfl_xor(s2, o2, 64);
    __shared__ float red[4];
    if ((t & 63) == 0) red[t>>6] = s2;
    __syncthreads();
    float S2 = red[0]+red[1]+red[2]+red[3];
    float scale = rsqrtf(S2*(1.f/DIN) + 1e-5f);
    #pragma unroll
    for (int i=0;i<4;i++){
        int idx = t + i*256;
        o[idx] = g[i]*scale*nw[idx];
    }
}

// ---------------- LayerNorm rows ----------------
__global__ __launch_bounds__(256) void ln_rows(
    const float* __restrict__ x, const float* __restrict__ w, const float* __restrict__ b,
    float* __restrict__ out, int D)
{
    int r = blockIdx.x, t = threadIdx.x;
    const float* xr = x + (size_t)r*D;
    float s = 0.f, s2 = 0.f;
    for (int i=t;i<D;i+=256){ float v = xr[i]; s += v; s2 += v*v; }
    #pragma unroll
    for (int o=32;o;o>>=1){ s += __shfl_xor(s,o,64); s2 += __shfl_xor(s2,o,64); }
    __shared__ float red[8];
    if ((t & 63) == 0){ red[t>>6] = s; red[4+(t>>6)] = s2; }
    __syncthreads();
    float S  = red[0]+red[1]+red[2]+red[3];
    float S2 = red[4]+red[5]+red[6]+red[7];
    float mean = S/D;
    float var  = S2/D - mean*mean;
    float inv  = rsqrtf(var + 1e-5f);
    for (int i=t;i<D;i+=256)
        out[(size_t)r*D + i] = (xr[i]-mean)*inv*w[i] + b[i];
}

// ---------------- cross-attention core (QKV from partials + bias) ----------------
template<int LQ, int LKV, int NS>
__global__ __launch_bounds__(64) void mha_attn(
    const float* __restrict__ pq, const float* __restrict__ pk, const float* __restrict__ pv,
    const float* __restrict__ qb, const float* __restrict__ kb, const float* __restrict__ vb,
    float* __restrict__ out, int Mq, int Mkv)
{
    const int hh = blockIdx.x, b = blockIdx.y, t = threadIdx.x;
    const size_t strQ = (size_t)Mq*DM, strKV = (size_t)Mkv*DM;
    __shared__ float ks[LKV*64], vs[LKV*64];
    const float kbv = kb[hh*64+t], vbv = vb[hh*64+t];
    for (int r=0;r<LKV;r++){
        const size_t off = (size_t)(b*LKV+r)*DM + hh*64 + t;
        float kv = kbv, vv = vbv;
        #pragma unroll
        for (int s=0;s<NS;s++){ kv += pk[s*strKV + off]; vv += pv[s*strKV + off]; }
        ks[r*64+t] = kv; vs[r*64+t] = vv;
    }
    __syncthreads();
    if (t < LQ) {
        float q[64];
        const size_t qoff = (size_t)(b*LQ+t)*DM + hh*64;
        #pragma unroll
        for (int d=0;d<64;d++){
            float qv = qb[hh*64+d];
            #pragma unroll
            for (int s=0;s<NS;s++) qv += pq[s*strQ + qoff + d];
            q[d] = qv;
        }
        float sc[LKV]; float mx = -1e30f;
        #pragma unroll
        for (int j=0;j<LKV;j++){
            float s = 0.f;
            #pragma unroll
            for (int d=0;d<64;d++) s += q[d]*ks[j*64+d];
            s *= 0.125f;
            sc[j] = s; mx = fmaxf(mx, s);
        }
        float se = 0.f;
        #pragma unroll
        for (int j=0;j<LKV;j++){ sc[j] = expf(sc[j]-mx); se += sc[j]; }
        float inv = 1.f/se;
        float* orow = out + (size_t)(b*LQ+t)*DM + hh*64;
        #pragma unroll
        for (int d=0;d<64;d++){
            float o = 0.f;
            #pragma unroll
            for (int j=0;j<LKV;j++) o += sc[j]*vs[j*64+d];
            orow[d] = o*inv;
        }
    }
}

// ---------------- mean pool (concat) ----------------
__global__ __launch_bounds__(512) void meanpool(
    const float* __restrict__ xs, const float* __restrict__ xg, float* __restrict__ fused)
{
    int b = blockIdx.x, d = threadIdx.x;
    float s = 0.f;
    for (int l=0;l<LS;l++) s += xs[(size_t)(b*LS+l)*DM + d];
    fused[b*1024 + d] = s*(1.f/LS);
    float g = 0.f;
    for (int l=0;l<LG;l++) g += xg[(size_t)(b*LG+l)*DM + d];
    fused[b*1024 + 512 + d] = g*(1.f/LG);
}

// ---------------- classifier head ----------------
__global__ __launch_bounds__(64) void cls_head(
    const float* __restrict__ lnf, const float* __restrict__ w,
    const float* __restrict__ bias, float* __restrict__ out)
{
    int b = blockIdx.x, t = threadIdx.x;
    __shared__ float xr[1024];
    for (int i=t;i<1024;i+=64) xr[i] = lnf[b*1024+i];
    __syncthreads();
    if (t < 55){
        float a = bias[t];
        const float* wr = w + (size_t)t*1024;
        for (int k=0;k<1024;k++) a += xr[k]*wr[k];
        out[b*55 + t] = a;
    }
}

// ---------------- launch ----------------
extern "C" void kernel_launch(void* const* d_in, const int* in_sizes, int n_in,
                              void* d_out, int out_size, void* d_ws, size_t ws_size,
                              hipStream_t stream)
{
    (void)in_sizes; (void)n_in; (void)out_size; (void)ws_size;
    const float* x_spectra = (const float*)d_in[0];
    const float* x_gaia    = (const float*)d_in[1];
    const float* tok_w_s   = (const float*)d_in[2];
    const float* tok_b_s   = (const float*)d_in[3];
    const float* tok_w_g   = (const float*)d_in[4];
    const float* tok_b_g   = (const float*)d_in[5];
    const float* ms_Win    = (const float*)d_in[6];
    const float* ms_conv_w = (const float*)d_in[7];
    const float* ms_conv_b = (const float*)d_in[8];
    const float* ms_dtb    = (const float*)d_in[9];
    const float* ms_Alog   = (const float*)d_in[10];
    const float* ms_D      = (const float*)d_in[11];
    const float* ms_nw     = (const float*)d_in[12];
    const float* ms_Wout   = (const float*)d_in[13];
    const float* mg_Win    = (const float*)d_in[14];
    const float* mg_conv_w = (const float*)d_in[15];
    const float* mg_conv_b = (const float*)d_in[16];
    const float* mg_dtb    = (const float*)d_in[17];
    const float* mg_Alog   = (const float*)d_in[18];
    const float* mg_D      = (const float*)d_in[19];
    const float* mg_nw     = (const float*)d_in[20];
    const float* mg_Wout   = (const float*)d_in[21];
    const float* cas_ln_w  = (const float*)d_in[22];
    const float* cas_ln_b  = (const float*)d_in[23];
    const float* cas_in_w  = (const float*)d_in[24];
    const float* cas_in_b  = (const float*)d_in[25];
    const float* cas_out_w = (const float*)d_in[26];
    const float* cas_out_b = (const float*)d_in[27];
    const float* cag_ln_w  = (const float*)d_in[28];
    const float* cag_ln_b  = (const float*)d_in[29];
    const float* cag_in_w  = (const float*)d_in[30];
    const float* cag_in_b  = (const float*)d_in[31];
    const float* cag_out_w = (const float*)d_in[32];
    const float* cag_out_b = (const float*)d_in[33];
    const float* cls_ln_w  = (const float*)d_in[34];
    const float* cls_ln_b  = (const float*)d_in[35];
    const float* cls_w     = (const float*)d_in[36];
    const float* cls_b     = (const float*)d_in[37];

    float* p = (float*)d_ws;
    auto alloc = [&](size_t n){ float* r = p; p += n; return r; };
    float* xs       = alloc((size_t)RS*DM);
    float* xg       = alloc((size_t)RG*DM);
    float* y_s      = alloc((size_t)RS*DIN);
    float* y_g      = alloc((size_t)RG*DIN);
    float* yn_s     = alloc((size_t)RS*DIN);
    float* yn_g     = alloc((size_t)RG*DIN);
    float* lnbuf    = alloc((size_t)RS*DM);
    float* attn_out = alloc((size_t)RS*DM);
    float* fused    = alloc((size_t)BB*1024);
    float* lnf      = alloc((size_t)BB*1024);
    float* part_inS  = alloc((size_t)SP_IN*RS*DPROJ);
    float* part_inG  = alloc((size_t)SP_IN*RG*DPROJ);
    float* part_outS = alloc((size_t)SP_OUT*RS*DM);
    float* part_outG = alloc((size_t)SP_OUT*RG*DM);
    float* part_q    = alloc((size_t)SP_ATT*RS*DM);
    float* part_k    = alloc((size_t)SP_ATT*RS*DM);
    float* part_v    = alloc((size_t)SP_ATT*RS*DM);

    // tokenize
    tokenize_k<<<dim3(LS,BB), 512, 0, stream>>>(x_spectra, tok_w_s, tok_b_s, xs, 3647, 64, LS);
    tokenize_k<<<dim3(LG,BB), 512, 0, stream>>>(x_gaia,    tok_w_g, tok_b_g, xg, 18,   2,  LG);

    const int rblkS = (RS*DM + 1023)/1024;   // 228 blocks for spectra-sized reduce

    // mamba stacks
    for (int i=0;i<NLAY;i++){
        const float* Win_s  = ms_Win  + (size_t)i*DM*DPROJ;
        const float* Win_g  = mg_Win  + (size_t)i*DM*DPROJ;
        const float* cw_s   = ms_conv_w + (size_t)i*1280*4;
        const float* cw_g   = mg_conv_w + (size_t)i*1280*4;
        const float* cbv_s  = ms_conv_b + (size_t)i*1280;
        const float* cbv_g  = mg_conv_b + (size_t)i*1280;
        const float* dtb_s  = ms_dtb  + (size_t)i*NH;
        const float* dtb_g  = mg_dtb  + (size_t)i*NH;
        const float* al_s   = ms_Alog + (size_t)i*NH;
        const float* al_g   = mg_Alog + (size_t)i*NH;
        const float* Dw_s   = ms_D    + (size_t)i*NH;
        const float* Dw_g   = mg_D    + (size_t)i*NH;
        const float* nw_s   = ms_nw   + (size_t)i*DIN;
        const float* nw_g   = mg_nw   + (size_t)i*DIN;
        const float* Wout_s = ms_Wout + (size_t)i*DIN*DM;
        const float* Wout_g = mg_Wout + (size_t)i*DIN*DM;

        GemmJob inS{xs, Win_s, part_inS, RS};
        GemmJob inG{xg, Win_g, part_inG, RG};
        gemm_ps<128,8,false,SP_IN><<<dim3((DPROJ+127)/128, 8, 2*SP_IN), 256, 0, stream>>>(
            inS, inG, inG, DPROJ, DM);

        mamba_scan<<<dim3(NH, BB, 2), 256, 0, stream>>>(
            part_inS, part_inG, cw_s, cw_g, cbv_s, cbv_g, dtb_s, dtb_g, al_s, al_g, Dw_s, Dw_g, y_s, y_g);

        gated_rmsnorm<<<dim3(RS+RG), 256, 0, stream>>>(
            y_s, part_inS, nw_s, yn_s,  y_g, part_inG, nw_g, yn_g);

        GemmJob outS{yn_s, Wout_s, part_outS, RS};
        GemmJob outG{yn_g, Wout_g, part_outG, RG};
        gemm_ps<64,4,false,SP_OUT><<<dim3(DM/64, 8, 2*SP_OUT), 256, 0, stream>>>(
            outS, outG, outG, DM, DIN);

        RJob roS{part_outS, nullptr, nullptr, xs, RS};
        RJob roG{part_outG, nullptr, nullptr, xg, RG};
        reduce_k<SP_OUT><<<dim3(rblkS, 2), 256, 0, stream>>>(roS, roG, DM);
    }

    // cross-attention: xs = xs + MHA(LN(xs), xg)
    {
        ln_rows<<<dim3(RS), 256, 0, stream>>>(xs, cas_ln_w, cas_ln_b, lnbuf, DM);
        GemmJob jq{lnbuf, cas_in_w,            part_q, RS};
        GemmJob jk{xg,    cas_in_w +  512*512, part_k, RG};
        GemmJob jv{xg,    cas_in_w + 1024*512, part_v, RG};
        gemm_ps<64,4,true,SP_ATT><<<dim3(DM/64, 8, 3*SP_ATT), 256, 0, stream>>>(jq, jk, jv, DM, DM);
        mha_attn<LS,LG,SP_ATT><<<dim3(8,BB), 64, 0, stream>>>(
            part_q, part_k, part_v, cas_in_b, cas_in_b+512, cas_in_b+1024, attn_out, RS, RG);
        GemmJob jo{attn_out, cas_out_w, part_outS, RS};
        gemm_ps<64,4,true,SP_ATT><<<dim3(DM/64, 8, SP_ATT), 256, 0, stream>>>(jo, jo, jo, DM, DM);
        RJob ro{part_outS, cas_out_b, xs, xs, RS};
        reduce_k<SP_ATT><<<dim3(rblkS, 1), 256, 0, stream>>>(ro, ro, DM);
    }

    // cross-attention: xg = xg + MHA(LN(xg), xs_updated)
    {
        ln_rows<<<dim3(RG), 256, 0, stream>>>(xg, cag_ln_w, cag_ln_b, lnbuf, DM);
        GemmJob jq{lnbuf, cag_in_w,            part_q, RG};
        GemmJob jk{xs,    cag_in_w +  512*512, part_k, RS};
        GemmJob jv{xs,    cag_in_w + 1024*512, part_v, RS};
        gemm_ps<64,4,true,SP_ATT><<<dim3(DM/64, 8, 3*SP_ATT), 256, 0, stream>>>(jq, jk, jv, DM, DM);
        mha_attn<LG,LS,SP_ATT><<<dim3(8,BB), 64, 0, stream>>>(
            part_q, part_k, part_v, cag_in_b, cag_in_b+512, cag_in_b+1024, attn_out, RG, RS);
        GemmJob jo{attn_out, cag_out_w, part_outS, RG};
        gemm_ps<64,4,true,SP_ATT><<<dim3(DM/64, 2, SP_ATT), 256, 0, stream>>>(jo, jo, jo, DM, DM);
        RJob ro{part_outS, cag_out_b, xg, xg, RG};
        reduce_k<SP_ATT><<<dim3((RG*DM+1023)/1024, 1), 256, 0, stream>>>(ro, ro, DM);
    }

    // head
    meanpool<<<dim3(BB), 512, 0, stream>>>(xs, xg, fused);
    ln_rows<<<dim3(BB), 256, 0, stream>>>(fused, cls_ln_w, cls_ln_b, lnf, 1024);
    cls_head<<<dim3(BB), 64, 0, stream>>>(lnf, cls_w, cls_b, (float*)d_out);
}

// Round 4
// 1417.895 us; speedup vs baseline: 1.2979x; 1.2979x over previous
//
#include <hip/hip_runtime.h>
#include <cmath>

// ---------------- constants ----------------
constexpr int BB    = 8;     // batch
constexpr int LS    = 57;    // spectra tokens
constexpr int LG    = 9;     // gaia tokens
constexpr int RS    = BB*LS; // 456
constexpr int RG    = BB*LG; // 72
constexpr int DM    = 512;   // d_model
constexpr int DPROJ = 2320;
constexpr int DIN   = 1024;
constexpr int NH    = 16;    // mamba heads
constexpr int HD    = 64;    // mamba headdim
constexpr int NLAY  = 10;

constexpr int SP_IN  = 4;    // split-K for in-proj  (K=512  -> 128/split)
constexpr int SP_OUT = 8;    // split-K for out-proj (K=1024 -> 128/split)
constexpr int SP_ATT = 4;    // split-K for attention gemms (K=512 -> 128/split)

__device__ __forceinline__ float siluf(float x){ return x / (1.f + expf(-x)); }

// ---------------- tokenize ----------------
__global__ __launch_bounds__(512) void tokenize_k(
    const float* __restrict__ x, const float* __restrict__ w, const float* __restrict__ bias,
    float* __restrict__ out, int in_dim, int tok_dim, int ntok)
{
    int t = blockIdx.x, b = blockIdx.y, d = threadIdx.x;
    __shared__ float xv[64];
    if (d < tok_dim) {
        int idx = t*tok_dim + d;
        xv[d] = (idx < in_dim) ? x[(size_t)b*in_dim + idx] : 0.f;
    }
    __syncthreads();
    float acc = bias[d];
    for (int k=0;k<tok_dim;k++) acc += xv[k]*w[(size_t)k*DM + d];
    out[(size_t)(b*ntok + t)*DM + d] = acc;
}

// ---------------- split-K f32 GEMM -> partials ----------------
struct GemmJob {
    const float* A; const float* B; float* part; int M;
};

template<int BN, int TN, bool TB, int NSPLIT>
__global__ __launch_bounds__(256) void gemm_ps(GemmJob j0, GemmJob j1, GemmJob j2, int N, int K)
{
    const int z = blockIdx.z;
    const int job = z / NSPLIT, split = z % NSPLIT;
    GemmJob jb = (job==0) ? j0 : (job==1 ? j1 : j2);
    const int bm = blockIdx.y*64, bn = blockIdx.x*BN;
    const int M = jb.M;
    if (bm >= M) return;
    __shared__ float As[2][16][68];
    __shared__ float Bs[2][16][BN+4];
    const int tid = threadIdx.x, tx = tid & 15, ty = tid >> 4;
    const float* __restrict__ A  = jb.A;
    const float* __restrict__ Bm = jb.B;
    float acc[4][TN] = {};

    const int arow = tid>>2, akb = (tid&3)*4;
    float4 ra, rb0, rb1;

    auto zero4 = [](){ float4 zz; zz.x=0.f; zz.y=0.f; zz.z=0.f; zz.w=0.f; return zz; };

    auto loadT = [&](int k0){
        ra = (bm+arow < M) ? *(const float4*)(A + (size_t)(bm+arow)*K + k0 + akb) : zero4();
        if constexpr (!TB) {
            const int kr = tid>>4, c4 = (tid&15)*4;
            rb0 = (bn+c4 < N) ? *(const float4*)(Bm + (size_t)(k0+kr)*N + bn + c4) : zero4();
            if constexpr (TN==8)
                rb1 = (bn+64+c4 < N) ? *(const float4*)(Bm + (size_t)(k0+kr)*N + bn + 64 + c4) : zero4();
        } else {
            const int nr = tid>>2, kb = (tid&3)*4;
            rb0 = (bn+nr < N) ? *(const float4*)(Bm + (size_t)(bn+nr)*K + k0 + kb) : zero4();
        }
    };
    auto storeT = [&](int buf){
        As[buf][akb+0][arow] = ra.x;
        As[buf][akb+1][arow] = ra.y;
        As[buf][akb+2][arow] = ra.z;
        As[buf][akb+3][arow] = ra.w;
        if constexpr (!TB) {
            const int kr = tid>>4, c4 = (tid&15)*4;
            *(float4*)&Bs[buf][kr][c4] = rb0;
            if constexpr (TN==8) *(float4*)&Bs[buf][kr][64+c4] = rb1;
        } else {
            const int nr = tid>>2, kb = (tid&3)*4;
            Bs[buf][kb+0][nr] = rb0.x;
            Bs[buf][kb+1][nr] = rb0.y;
            Bs[buf][kb+2][nr] = rb0.z;
            Bs[buf][kb+3][nr] = rb0.w;
        }
    };

    const int Kper = K/NSPLIT;
    const int koff = split*Kper;
    const int nk = Kper/16;
    loadT(koff);
    storeT(0);
    __syncthreads();
    for (int t=0; t<nk; ++t){
        const int cur = t & 1;
        if (t+1 < nk) loadT(koff + (t+1)*16);
        #pragma unroll
        for (int kk=0; kk<16; ++kk){
            float4 av = *(const float4*)&As[cur][kk][ty*4];
            float a[4] = {av.x, av.y, av.z, av.w};
            float b[TN];
            #pragma unroll
            for (int g=0; g<TN/4; ++g){
                float4 bv = *(const float4*)&Bs[cur][kk][tx*TN + g*4];
                b[g*4+0]=bv.x; b[g*4+1]=bv.y; b[g*4+2]=bv.z; b[g*4+3]=bv.w;
            }
            #pragma unroll
            for (int i=0;i<4;i++)
                #pragma unroll
                for (int j=0;j<TN;j++) acc[i][j] = fmaf(a[i], b[j], acc[i][j]);
        }
        if (t+1 < nk) storeT(cur^1);
        __syncthreads();
    }

    float* __restrict__ P = jb.part + (size_t)split*M*N;
    #pragma unroll
    for (int i=0;i<4;i++){
        int m = bm + ty*4 + i;
        if (m < M){
            #pragma unroll
            for (int j=0;j<TN;j++){
                int n = bn + tx*TN + j;
                if (n < N) P[(size_t)m*N + n] = acc[i][j];
            }
        }
    }
}

// ---------------- reduce partials (+bias, +res) ----------------
struct RJob { const float* part; const float* bias; const float* res; float* C; int M; };

template<int NS>
__global__ __launch_bounds__(256) void reduce_k(RJob j0, RJob j1, int N)
{
    RJob j = blockIdx.y ? j1 : j0;
    const size_t total = (size_t)j.M*N;
    const size_t i4 = ((size_t)blockIdx.x*256 + threadIdx.x)*4;
    if (i4 >= total) return;
    float4 s = *(const float4*)(j.part + i4);
    #pragma unroll
    for (int t=1;t<NS;t++){
        const float4 v = *(const float4*)(j.part + (size_t)t*total + i4);
        s.x+=v.x; s.y+=v.y; s.z+=v.z; s.w+=v.w;
    }
    const int n = (int)(i4 % (size_t)N);
    if (j.bias){ s.x+=j.bias[n]; s.y+=j.bias[n+1]; s.z+=j.bias[n+2]; s.w+=j.bias[n+3]; }
    if (j.res){ const float4 r = *(const float4*)(j.res + i4); s.x+=r.x; s.y+=r.y; s.z+=r.z; s.w+=r.w; }
    *(float4*)(j.C + i4) = s;
}

// ---------------- fused conv1d+silu+softplus+SSM scan ----------------
// One block per (head, batch, stack). Phase 1: stream zx through register conv
// windows, store silu(conv) for ALL steps into LDS; 57 threads precompute
// softplus(dt)+exp. ONE barrier. Phase 2: 57-step recurrence entirely from
// LDS (no global loads, no barriers, no transcendentals in the loop).
// LDS row layout (stride 352 floats): xh [0..63], B group ng at 64+ng*36,
// C group ng at 208+ng*36 (skew 36: 16B-aligned, disjoint banks across ng).
__global__ __launch_bounds__(256) void mamba_scan(
    const float* __restrict__ zx_s, const float* __restrict__ zx_g,
    const float* __restrict__ cw_s, const float* __restrict__ cw_g,
    const float* __restrict__ cb_s, const float* __restrict__ cb_g,
    const float* __restrict__ dtb_s, const float* __restrict__ dtb_g,
    const float* __restrict__ al_s, const float* __restrict__ al_g,
    const float* __restrict__ Dw_s, const float* __restrict__ Dw_g,
    float* __restrict__ y_s, float* __restrict__ y_g)
{
    const int h = blockIdx.x, b = blockIdx.y, st = blockIdx.z;
    const float* zx  = st ? zx_g  : zx_s;
    const float* cw  = st ? cw_g  : cw_s;
    const float* cb  = st ? cb_g  : cb_s;
    const float* dtb = st ? dtb_g : dtb_s;
    const float* al  = st ? al_g  : al_s;
    const float* Dw  = st ? Dw_g  : Dw_s;
    float* y = st ? y_g : y_s;
    const int L = st ? LG : LS;

    const int t = threadIdx.x;
    constexpr int RST = 352;
    __shared__ float cv[LS*RST];
    __shared__ float dts[LS], das[LS];

    auto lpos = [](int c)->int {
        if (c < 64) return c;
        if (c < 192){ int i = c-64;  return 64  + (i>>5)*36 + (i&31); }
        int i = c-192; return 208 + (i>>5)*36 + (i&31);
    };

    // channel A: c = t (0..255); channel B: c2 = 256+t (t<64)
    const int cA   = t;
    const int chA  = (cA < 64) ? (h*HD + cA) : (960 + cA);
    const int posA = lpos(cA);
    float wA[4]; float cbA;
    #pragma unroll
    for (int k=0;k<4;k++) wA[k] = cw[chA*4 + k];
    cbA = cb[chA];
    const bool hasB = (t < 64);
    const int chB  = 1216 + t;
    const int posB = lpos(256 + t);
    float wB[4] = {0,0,0,0}; float cbB = 0.f;
    if (hasB) {
        #pragma unroll
        for (int k=0;k<4;k++) wB[k] = cw[chB*4 + k];
        cbB = cb[chB];
    }

    const float Ah     = -expf(al[h]);
    const float dtbias = dtb[h];
    const float Dh     = Dw[h];

    // ---- phase 1: conv + silu for all steps ----
    {
        float a0=0.f, a1=0.f, a2=0.f, b0=0.f, b1=0.f, b2=0.f;
        const float* zA = zx + (size_t)b*L*DPROJ + 1024 + chA;
        const float* zB = zx + (size_t)b*L*DPROJ + 1024 + chB;
        #pragma unroll 4
        for (int l=0; l<L; ++l){
            const float rawA = zA[(size_t)l*DPROJ];
            float acc = cbA + wA[0]*a0 + wA[1]*a1 + wA[2]*a2 + wA[3]*rawA;
            cv[l*RST + posA] = siluf(acc);
            a0=a1; a1=a2; a2=rawA;
            if (hasB){
                const float rawB = zB[(size_t)l*DPROJ];
                float accB = cbB + wB[0]*b0 + wB[1]*b1 + wB[2]*b2 + wB[3]*rawB;
                cv[l*RST + posB] = siluf(accB);
                b0=b1; b1=b2; b2=rawB;
            }
        }
    }
    if (t < L){
        float dtv = zx[((size_t)(b*L + t))*DPROJ + 2304 + h] + dtbias;
        dtv = (dtv > 20.f) ? dtv : log1pf(expf(dtv));
        dts[t] = dtv;
        das[t] = expf(dtv * Ah);
    }
    __syncthreads();

    // ---- phase 2: serial recurrence from LDS ----
    const int p = t >> 2, ng = t & 3;
    const int bB = 64  + ng*36;
    const int bC = 208 + ng*36;
    float hst[32];
    #pragma unroll
    for (int j=0;j<32;j++) hst[j] = 0.f;

    for (int l=0; l<L; ++l){
        const float dtv  = dts[l];
        const float dA   = das[l];
        const float xh   = cv[l*RST + p];
        const float coef = dtv * xh;
        const float* Bv  = &cv[l*RST + bB];
        const float* Cv  = &cv[l*RST + bC];
        float ysum = 0.f;
        #pragma unroll
        for (int j=0;j<32;j++){
            hst[j] = dA*hst[j] + coef*Bv[j];
            ysum  += hst[j]*Cv[j];
        }
        ysum += __shfl_xor(ysum, 1, 64);
        ysum += __shfl_xor(ysum, 2, 64);
        if (ng == 0)
            y[((size_t)(b*L + l))*DIN + h*HD + p] = ysum + Dh*xh;
    }
}

// ---------------- gated RMSNorm (both stacks in one grid) ----------------
__global__ __launch_bounds__(256) void gated_rmsnorm(
    const float* __restrict__ y_s, const float* __restrict__ zx_s, const float* __restrict__ nw_s, float* __restrict__ o_s,
    const float* __restrict__ y_g, const float* __restrict__ zx_g, const float* __restrict__ nw_g, float* __restrict__ o_g)
{
    int r = blockIdx.x, t = threadIdx.x;
    int st = (r >= RS);
    int row = st ? r - RS : r;
    const float* y  = (st ? y_g  : y_s)  + (size_t)row*DIN;
    const float* z  = (st ? zx_g : zx_s) + (size_t)row*DPROJ;
    const float* nw = st ? nw_g : nw_s;
    float* o = (st ? o_g : o_s) + (size_t)row*DIN;

    float g[4]; float s2 = 0.f;
    #pragma unroll
    for (int i=0;i<4;i++){
        int idx = t + i*256;
        float gv = y[idx] * siluf(z[idx]);
        g[i] = gv; s2 += gv*gv;
    }
    #pragma unroll
    for (int o2=32;o2;o2>>=1) s2 += __shfl_xor(s2, o2, 64);
    __shared__ float red[4];
    if ((t & 63) == 0) red[t>>6] = s2;
    __syncthreads();
    float S2 = red[0]+red[1]+red[2]+red[3];
    float scale = rsqrtf(S2*(1.f/DIN) + 1e-5f);
    #pragma unroll
    for (int i=0;i<4;i++){
        int idx = t + i*256;
        o[idx] = g[i]*scale*nw[idx];
    }
}

// ---------------- LayerNorm rows ----------------
__global__ __launch_bounds__(256) void ln_rows(
    const float* __restrict__ x, const float* __restrict__ w, const float* __restrict__ b,
    float* __restrict__ out, int D)
{
    int r = blockIdx.x, t = threadIdx.x;
    const float* xr = x + (size_t)r*D;
    float s = 0.f, s2 = 0.f;
    for (int i=t;i<D;i+=256){ float v = xr[i]; s += v; s2 += v*v; }
    #pragma unroll
    for (int o=32;o;o>>=1){ s += __shfl_xor(s,o,64); s2 += __shfl_xor(s2,o,64); }
    __shared__ float red[8];
    if ((t & 63) == 0){ red[t>>6] = s; red[4+(t>>6)] = s2; }
    __syncthreads();
    float S  = red[0]+red[1]+red[2]+red[3];
    float S2 = red[4]+red[5]+red[6]+red[7];
    float mean = S/D;
    float var  = S2/D - mean*mean;
    float inv  = rsqrtf(var + 1e-5f);
    for (int i=t;i<D;i+=256)
        out[(size_t)r*D + i] = (xr[i]-mean)*inv*w[i] + b[i];
}

// ---------------- cross-attention core (QKV from partials + bias) ----------------
template<int LQ, int LKV, int NS>
__global__ __launch_bounds__(64) void mha_attn(
    const float* __restrict__ pq, const float* __restrict__ pk, const float* __restrict__ pv,
    const float* __restrict__ qb, const float* __restrict__ kb, const float* __restrict__ vb,
    float* __restrict__ out, int Mq, int Mkv)
{
    const int hh = blockIdx.x, b = blockIdx.y, t = threadIdx.x;
    const size_t strQ = (size_t)Mq*DM, strKV = (size_t)Mkv*DM;
    __shared__ float ks[LKV*64], vs[LKV*64];
    const float kbv = kb[hh*64+t], vbv = vb[hh*64+t];
    for (int r=0;r<LKV;r++){
        const size_t off = (size_t)(b*LKV+r)*DM + hh*64 + t;
        float kv = kbv, vv = vbv;
        #pragma unroll
        for (int s=0;s<NS;s++){ kv += pk[s*strKV + off]; vv += pv[s*strKV + off]; }
        ks[r*64+t] = kv; vs[r*64+t] = vv;
    }
    __syncthreads();
    if (t < LQ) {
        float q[64];
        const size_t qoff = (size_t)(b*LQ+t)*DM + hh*64;
        #pragma unroll
        for (int d=0;d<64;d++){
            float qv = qb[hh*64+d];
            #pragma unroll
            for (int s=0;s<NS;s++) qv += pq[s*strQ + qoff + d];
            q[d] = qv;
        }
        float sc[LKV]; float mx = -1e30f;
        #pragma unroll
        for (int j=0;j<LKV;j++){
            float s = 0.f;
            #pragma unroll
            for (int d=0;d<64;d++) s += q[d]*ks[j*64+d];
            s *= 0.125f;
            sc[j] = s; mx = fmaxf(mx, s);
        }
        float se = 0.f;
        #pragma unroll
        for (int j=0;j<LKV;j++){ sc[j] = expf(sc[j]-mx); se += sc[j]; }
        float inv = 1.f/se;
        float* orow = out + (size_t)(b*LQ+t)*DM + hh*64;
        #pragma unroll
        for (int d=0;d<64;d++){
            float o = 0.f;
            #pragma unroll
            for (int j=0;j<LKV;j++) o += sc[j]*vs[j*64+d];
            orow[d] = o*inv;
        }
    }
}

// ---------------- mean pool (concat) ----------------
__global__ __launch_bounds__(512) void meanpool(
    const float* __restrict__ xs, const float* __restrict__ xg, float* __restrict__ fused)
{
    int b = blockIdx.x, d = threadIdx.x;
    float s = 0.f;
    for (int l=0;l<LS;l++) s += xs[(size_t)(b*LS+l)*DM + d];
    fused[b*1024 + d] = s*(1.f/LS);
    float g = 0.f;
    for (int l=0;l<LG;l++) g += xg[(size_t)(b*LG+l)*DM + d];
    fused[b*1024 + 512 + d] = g*(1.f/LG);
}

// ---------------- classifier head ----------------
__global__ __launch_bounds__(64) void cls_head(
    const float* __restrict__ lnf, const float* __restrict__ w,
    const float* __restrict__ bias, float* __restrict__ out)
{
    int b = blockIdx.x, t = threadIdx.x;
    __shared__ float xr[1024];
    for (int i=t;i<1024;i+=64) xr[i] = lnf[b*1024+i];
    __syncthreads();
    if (t < 55){
        float a = bias[t];
        const float* wr = w + (size_t)t*1024;
        for (int k=0;k<1024;k++) a += xr[k]*wr[k];
        out[b*55 + t] = a;
    }
}

// ---------------- launch ----------------
extern "C" void kernel_launch(void* const* d_in, const int* in_sizes, int n_in,
                              void* d_out, int out_size, void* d_ws, size_t ws_size,
                              hipStream_t stream)
{
    (void)in_sizes; (void)n_in; (void)out_size; (void)ws_size;
    const float* x_spectra = (const float*)d_in[0];
    const float* x_gaia    = (const float*)d_in[1];
    const float* tok_w_s   = (const float*)d_in[2];
    const float* tok_b_s   = (const float*)d_in[3];
    const float* tok_w_g   = (const float*)d_in[4];
    const float* tok_b_g   = (const float*)d_in[5];
    const float* ms_Win    = (const float*)d_in[6];
    const float* ms_conv_w = (const float*)d_in[7];
    const float* ms_conv_b = (const float*)d_in[8];
    const float* ms_dtb    = (const float*)d_in[9];
    const float* ms_Alog   = (const float*)d_in[10];
    const float* ms_D      = (const float*)d_in[11];
    const float* ms_nw     = (const float*)d_in[12];
    const float* ms_Wout   = (const float*)d_in[13];
    const float* mg_Win    = (const float*)d_in[14];
    const float* mg_conv_w = (const float*)d_in[15];
    const float* mg_conv_b = (const float*)d_in[16];
    const float* mg_dtb    = (const float*)d_in[17];
    const float* mg_Alog   = (const float*)d_in[18];
    const float* mg_D      = (const float*)d_in[19];
    const float* mg_nw     = (const float*)d_in[20];
    const float* mg_Wout   = (const float*)d_in[21];
    const float* cas_ln_w  = (const float*)d_in[22];
    const float* cas_ln_b  = (const float*)d_in[23];
    const float* cas_in_w  = (const float*)d_in[24];
    const float* cas_in_b  = (const float*)d_in[25];
    const float* cas_out_w = (const float*)d_in[26];
    const float* cas_out_b = (const float*)d_in[27];
    const float* cag_ln_w  = (const float*)d_in[28];
    const float* cag_ln_b  = (const float*)d_in[29];
    const float* cag_in_w  = (const float*)d_in[30];
    const float* cag_in_b  = (const float*)d_in[31];
    const float* cag_out_w = (const float*)d_in[32];
    const float* cag_out_b = (const float*)d_in[33];
    const float* cls_ln_w  = (const float*)d_in[34];
    const float* cls_ln_b  = (const float*)d_in[35];
    const float* cls_w     = (const float*)d_in[36];
    const float* cls_b     = (const float*)d_in[37];

    float* p = (float*)d_ws;
    auto alloc = [&](size_t n){ float* r = p; p += n; return r; };
    float* xs       = alloc((size_t)RS*DM);
    float* xg       = alloc((size_t)RG*DM);
    float* y_s      = alloc((size_t)RS*DIN);
    float* y_g      = alloc((size_t)RG*DIN);
    float* yn_s     = alloc((size_t)RS*DIN);
    float* yn_g     = alloc((size_t)RG*DIN);
    float* lnbuf    = alloc((size_t)RS*DM);
    float* attn_out = alloc((size_t)RS*DM);
    float* fused    = alloc((size_t)BB*1024);
    float* lnf      = alloc((size_t)BB*1024);
    float* part_inS  = alloc((size_t)SP_IN*RS*DPROJ);
    float* part_inG  = alloc((size_t)SP_IN*RG*DPROJ);
    float* part_outS = alloc((size_t)SP_OUT*RS*DM);
    float* part_outG = alloc((size_t)SP_OUT*RG*DM);
    // union region: {zx_s, zx_g} during layers; {part_q,k,v} during cross-attn
    float* uni       = alloc((size_t)3*SP_ATT*RS*DM);
    float* zx_s   = uni;
    float* zx_g   = uni + (size_t)RS*DPROJ;
    float* part_q = uni;
    float* part_k = uni + (size_t)SP_ATT*RS*DM;
    float* part_v = uni + (size_t)2*SP_ATT*RS*DM;

    // tokenize
    tokenize_k<<<dim3(LS,BB), 512, 0, stream>>>(x_spectra, tok_w_s, tok_b_s, xs, 3647, 64, LS);
    tokenize_k<<<dim3(LG,BB), 512, 0, stream>>>(x_gaia,    tok_w_g, tok_b_g, xg, 18,   2,  LG);

    const int rblkS  = (RS*DM + 1023)/1024;      // out-proj reduce blocks
    const int rblkIn = (RS*DPROJ + 1023)/1024;   // in-proj reduce blocks

    // mamba stacks
    for (int i=0;i<NLAY;i++){
        const float* Win_s  = ms_Win  + (size_t)i*DM*DPROJ;
        const float* Win_g  = mg_Win  + (size_t)i*DM*DPROJ;
        const float* cw_s   = ms_conv_w + (size_t)i*1280*4;
        const float* cw_g   = mg_conv_w + (size_t)i*1280*4;
        const float* cbv_s  = ms_conv_b + (size_t)i*1280;
        const float* cbv_g  = mg_conv_b + (size_t)i*1280;
        const float* dtb_s  = ms_dtb  + (size_t)i*NH;
        const float* dtb_g  = mg_dtb  + (size_t)i*NH;
        const float* al_s   = ms_Alog + (size_t)i*NH;
        const float* al_g   = mg_Alog + (size_t)i*NH;
        const float* Dw_s   = ms_D    + (size_t)i*NH;
        const float* Dw_g   = mg_D    + (size_t)i*NH;
        const float* nw_s   = ms_nw   + (size_t)i*DIN;
        const float* nw_g   = mg_nw   + (size_t)i*DIN;
        const float* Wout_s = ms_Wout + (size_t)i*DIN*DM;
        const float* Wout_g = mg_Wout + (size_t)i*DIN*DM;

        GemmJob inS{xs, Win_s, part_inS, RS};
        GemmJob inG{xg, Win_g, part_inG, RG};
        gemm_ps<128,8,false,SP_IN><<<dim3((DPROJ+127)/128, 8, 2*SP_IN), 256, 0, stream>>>(
            inS, inG, inG, DPROJ, DM);

        RJob riS{part_inS, nullptr, nullptr, zx_s, RS};
        RJob riG{part_inG, nullptr, nullptr, zx_g, RG};
        reduce_k<SP_IN><<<dim3(rblkIn, 2), 256, 0, stream>>>(riS, riG, DPROJ);

        mamba_scan<<<dim3(NH, BB, 2), 256, 0, stream>>>(
            zx_s, zx_g, cw_s, cw_g, cbv_s, cbv_g, dtb_s, dtb_g, al_s, al_g, Dw_s, Dw_g, y_s, y_g);

        gated_rmsnorm<<<dim3(RS+RG), 256, 0, stream>>>(
            y_s, zx_s, nw_s, yn_s,  y_g, zx_g, nw_g, yn_g);

        GemmJob outS{yn_s, Wout_s, part_outS, RS};
        GemmJob outG{yn_g, Wout_g, part_outG, RG};
        gemm_ps<64,4,false,SP_OUT><<<dim3(DM/64, 8, 2*SP_OUT), 256, 0, stream>>>(
            outS, outG, outG, DM, DIN);

        RJob roS{part_outS, nullptr, nullptr, xs, RS};
        RJob roG{part_outG, nullptr, nullptr, xg, RG};
        reduce_k<SP_OUT><<<dim3(rblkS, 2), 256, 0, stream>>>(roS, roG, DM);
    }

    // cross-attention: xs = xs + MHA(LN(xs), xg)
    {
        ln_rows<<<dim3(RS), 256, 0, stream>>>(xs, cas_ln_w, cas_ln_b, lnbuf, DM);
        GemmJob jq{lnbuf, cas_in_w,            part_q, RS};
        GemmJob jk{xg,    cas_in_w +  512*512, part_k, RG};
        GemmJob jv{xg,    cas_in_w + 1024*512, part_v, RG};
        gemm_ps<64,4,true,SP_ATT><<<dim3(DM/64, 8, 3*SP_ATT), 256, 0, stream>>>(jq, jk, jv, DM, DM);
        mha_attn<LS,LG,SP_ATT><<<dim3(8,BB), 64, 0, stream>>>(
            part_q, part_k, part_v, cas_in_b, cas_in_b+512, cas_in_b+1024, attn_out, RS, RG);
        GemmJob jo{attn_out, cas_out_w, part_outS, RS};
        gemm_ps<64,4,true,SP_ATT><<<dim3(DM/64, 8, SP_ATT), 256, 0, stream>>>(jo, jo, jo, DM, DM);
        RJob ro{part_outS, cas_out_b, xs, xs, RS};
        reduce_k<SP_ATT><<<dim3(rblkS, 1), 256, 0, stream>>>(ro, ro, DM);
    }

    // cross-attention: xg = xg + MHA(LN(xg), xs_updated)
    {
        ln_rows<<<dim3(RG), 256, 0, stream>>>(xg, cag_ln_w, cag_ln_b, lnbuf, DM);
        GemmJob jq{lnbuf, cag_in_w,            part_q, RG};
        GemmJob jk{xs,    cag_in_w +  512*512, part_k, RS};
        GemmJob jv{xs,    cag_in_w + 1024*512, part_v, RS};
        gemm_ps<64,4,true,SP_ATT><<<dim3(DM/64, 8, 3*SP_ATT), 256, 0, stream>>>(jq, jk, jv, DM, DM);
        mha_attn<LG,LS,SP_ATT><<<dim3(8,BB), 64, 0, stream>>>(
            part_q, part_k, part_v, cag_in_b, cag_in_b+512, cag_in_b+1024, attn_out, RG, RS);
        GemmJob jo{attn_out, cag_out_w, part_outS, RG};
        gemm_ps<64,4,true,SP_ATT><<<dim3(DM/64, 2, SP_ATT), 256, 0, stream>>>(jo, jo, jo, DM, DM);
        RJob ro{part_outS, cag_out_b, xg, xg, RG};
        reduce_k<SP_ATT><<<dim3((RG*DM+1023)/1024, 1), 256, 0, stream>>>(ro, ro, DM);
    }

    // head
    meanpool<<<dim3(BB), 512, 0, stream>>>(xs, xg, fused);
    ln_rows<<<dim3(BB), 256, 0, stream>>>(fused, cls_ln_w, cls_ln_b, lnf, 1024);
    cls_head<<<dim3(BB), 64, 0, stream>>>(lnf, cls_w, cls_b, (float*)d_out);
}